// Round 5
// baseline (2338.048 us; speedup 1.0000x reference)
//
#include <hip/hip_runtime.h>

#define NN 100000
#define NE 1600000
#define HID 64
#define NL 3
#define BN_EPS 1e-5f
#define BSH 6
#define BNODES 64
#define NB 1563                // ceil(NN / BNODES)
#define PAD 68                 // LDS row stride (floats) to spread ds_add banks
#define BIN_CHUNK 16384
#define BIN_GRID ((NE + BIN_CHUNK - 1) / BIN_CHUNK)

__device__ __forceinline__ float bf2f(unsigned short u) {
    union { unsigned int i; float f; } v; v.i = ((unsigned int)u) << 16; return v.f;
}
__device__ __forceinline__ unsigned short f2bf(float f) {
    union { float f; unsigned int i; } v; v.f = f;
    unsigned int r = v.i + 0x7FFFu + ((v.i >> 16) & 1u);   // RNE
    return (unsigned short)(r >> 16);
}

// ---------------- input convert x f32 -> bf16 ----------------
__global__ void k_conv(const float* __restrict__ x, ushort* __restrict__ xb) {
    int i = blockIdx.x * blockDim.x + threadIdx.x;   // over NN*HID/4
    float4 v = ((const float4*)x)[i];
    ushort4 o;
    o.x = f2bf(v.x); o.y = f2bf(v.y); o.z = f2bf(v.z); o.w = f2bf(v.w);
    ((ushort4*)xb)[i] = o;
}

// ---------------- bucket histogram ----------------
__global__ void k_histB(const int* __restrict__ dst, int* __restrict__ ghist) {
    __shared__ int lh[NB];
    for (int i = threadIdx.x; i < NB; i += blockDim.x) lh[i] = 0;
    __syncthreads();
    int base = blockIdx.x * BIN_CHUNK;
    int end = min(base + BIN_CHUNK, NE);
    for (int e = base + threadIdx.x; e < end; e += blockDim.x)
        atomicAdd(&lh[dst[e] >> BSH], 1);
    __syncthreads();
    for (int i = threadIdx.x; i < NB; i += blockDim.x)
        if (lh[i]) atomicAdd(&ghist[i], lh[i]);
}

// ---------------- bucket scan: 1024 threads, 2 elems/thread ----------------
__global__ void k_scanB(const int* __restrict__ ghist, int* __restrict__ boff,
                        int* __restrict__ gcur) {
    __shared__ int t[1024];
    int tid = threadIdx.x;
    int i0 = 2 * tid, i1 = 2 * tid + 1;
    int v0 = (i0 < NB) ? ghist[i0] : 0;
    int v1 = (i1 < NB) ? ghist[i1] : 0;
    int s = v0 + v1;
    t[tid] = s;
    __syncthreads();
    for (int d = 1; d < 1024; d <<= 1) {
        int u = (tid >= d) ? t[tid - d] : 0;
        __syncthreads();
        t[tid] += u;
        __syncthreads();
    }
    int base = t[tid] - s;   // exclusive over pairs
    if (i0 < NB) { boff[i0] = base; gcur[i0] = base; }
    if (i1 < NB) { boff[i1] = base + v0; gcur[i1] = base + v0; }
    if (tid == 0) boff[NB] = NE;
}

// ---------------- binning: block-local hist -> bulk reserve -> write ----------------
__global__ void k_binB(const int* __restrict__ ei, const float* __restrict__ att,
                       int* __restrict__ gcur, int2* __restrict__ evb) {
    __shared__ int lh[NB];
    for (int i = threadIdx.x; i < NB; i += blockDim.x) lh[i] = 0;
    __syncthreads();
    int base = blockIdx.x * BIN_CHUNK;
    int end = min(base + BIN_CHUNK, NE);
    for (int e = base + threadIdx.x; e < end; e += blockDim.x)
        atomicAdd(&lh[ei[NE + e] >> BSH], 1);
    __syncthreads();
    for (int i = threadIdx.x; i < NB; i += blockDim.x) {
        int c = lh[i];
        lh[i] = c ? atomicAdd(&gcur[i], c) : 0;   // lh becomes running cursor
    }
    __syncthreads();
    for (int e = base + threadIdx.x; e < end; e += blockDim.x) {
        int d = ei[NE + e];
        int b = d >> BSH;
        int p = atomicAdd(&lh[b], 1);
        evb[p] = make_int2(ei[e] | ((d & (BNODES - 1)) << 17), __float_as_int(att[e]));
    }
}

// ------- agg: bucket scatter-add in LDS (+x) -> Linear1 (W in LDS) -> BN stats -------
__global__ __launch_bounds__(512, 8) void k_agg(const ushort* __restrict__ xb,
                                                const int* __restrict__ boff,
                                                const int2* __restrict__ evb,
                                                const float* __restrict__ W1,
                                                const float* __restrict__ b1,
                                                ushort* __restrict__ hout,
                                                float* __restrict__ stats) {
    __shared__ float acc[BNODES * PAD];    // 17408 B
    __shared__ float w1[HID * HID];        // 16384 B
    __shared__ float red[16][HID];         // 4096 B
    int tid = threadIdx.x;
    int wv = tid >> 6, c = tid & 63;
    int b = blockIdx.x;
    int node0 = b << BSH;
    int nvalid = min(BNODES, NN - node0);
    for (int i = tid; i < HID * HID; i += 512) w1[i] = W1[i];
    for (int i = tid; i < nvalid * HID; i += 512)
        acc[(i >> 6) * PAD + (i & 63)] = bf2f(xb[(size_t)node0 * HID + i]);
    __syncthreads();
    // edge phase: each quarter-wave owns one edge, ushort4 row load per lane
    int e0 = boff[b], e1 = boff[b + 1];
    int g = (tid >> 4) & 3;
    int li = tid & 15;
#pragma unroll 2
    for (int e = e0 + wv * 4; e < e1; e += 32) {
        int ee = e + g;
        int2 t = evb[(ee < e1) ? ee : (e1 - 1)];
        float a = (ee < e1) ? __int_as_float(t.y) : 0.f;
        int src = t.x & 0x1FFFF;
        int dl = t.x >> 17;
        ushort4 r4 = *(const ushort4*)(xb + (size_t)src * HID + li * 4);
        int base = dl * PAD + li * 4;
        atomicAdd(&acc[base + 0], bf2f(r4.x) * a);
        atomicAdd(&acc[base + 1], bf2f(r4.y) * a);
        atomicAdd(&acc[base + 2], bf2f(r4.z) * a);
        atomicAdd(&acc[base + 3], bf2f(r4.w) * a);
    }
    __syncthreads();
    // Linear1 + BN stats straight from LDS (W1 stride-1, row broadcast)
    float bl = b1[c];
    float s1 = 0.f, s2 = 0.f;
    for (int dl = wv; dl < nvalid; dl += 8) {
        const float4* rp = (const float4*)&acc[dl * PAD];
        float o = bl;
#pragma unroll
        for (int k4 = 0; k4 < 16; ++k4) {
            float4 rv = rp[k4];
            const float* wk = &w1[k4 * 4 * HID + c];
            o += rv.x * wk[0] + rv.y * wk[HID] + rv.z * wk[2 * HID] + rv.w * wk[3 * HID];
        }
        hout[(size_t)(node0 + dl) * HID + c] = f2bf(o);
        s1 += o;
        s2 += o * o;
    }
    red[wv][c] = s1;
    red[8 + wv][c] = s2;
    __syncthreads();
    if (wv == 0) {
        float t1 = 0.f, t2 = 0.f;
#pragma unroll
        for (int w = 0; w < 8; ++w) { t1 += red[w][c]; t2 += red[8 + w][c]; }
        atomicAdd(&stats[c], t1);
        atomicAdd(&stats[HID + c], t2);
    }
}

// ------- mlp2: BN -> ReLU -> Linear2 (W in LDS) -> ReLU -------
__global__ __launch_bounds__(256, 8) void k_mlp2(const float* __restrict__ W2,
                                                 const float* __restrict__ b2,
                                                 const float* __restrict__ gamma,
                                                 const float* __restrict__ beta,
                                                 const float* __restrict__ stats,
                                                 const ushort* __restrict__ h,
                                                 ushort* __restrict__ xb_out,
                                                 float* __restrict__ f_out,
                                                 int write_f32) {
    __shared__ float w2[HID * HID];        // 16 KB
    __shared__ float rowlds[4][HID];
    int tid = threadIdx.x, wv = tid >> 6, c = tid & 63;
    for (int i = tid; i < HID * HID; i += 256) w2[i] = W2[i];
    float bl = b2[c];
    float mu = stats[c] * (1.0f / NN);
    float var = fmaxf(stats[HID + c] * (1.0f / NN) - mu * mu, 0.f);
    float aC = gamma[c] * rsqrtf(var + BN_EPS);
    float bC = beta[c] - mu * aC;
    __syncthreads();
    int gw = blockIdx.x * 4 + wv, nw = gridDim.x * 4;
    for (int node = gw; node < NN; node += nw) {
        float v = bf2f(h[(size_t)node * HID + c]);
        v = fmaxf(aC * v + bC, 0.f);
        rowlds[wv][c] = v;                   // wave-local, no barrier needed
        float o = bl;
        const float4* rp = (const float4*)&rowlds[wv][0];
#pragma unroll
        for (int k4 = 0; k4 < 16; ++k4) {
            float4 rv = rp[k4];
            const float* wk = &w2[k4 * 4 * HID + c];
            o += rv.x * wk[0] + rv.y * wk[HID] + rv.z * wk[2 * HID] + rv.w * wk[3 * HID];
        }
        o = fmaxf(o, 0.f);
        if (write_f32) f_out[(size_t)node * HID + c] = o;
        else           xb_out[(size_t)node * HID + c] = f2bf(o);
    }
}

extern "C" void kernel_launch(void* const* d_in, const int* in_sizes, int n_in,
                              void* d_out, int out_size, void* d_ws, size_t ws_size,
                              hipStream_t stream) {
    const float* x_in  = (const float*)d_in[0];
    const int*   ei    = (const int*)d_in[1];
    const float* att   = (const float*)d_in[2];
    const float* W1    = (const float*)d_in[3];
    const float* b1    = (const float*)d_in[4];
    const float* gamma = (const float*)d_in[5];
    const float* beta  = (const float*)d_in[6];
    const float* W2    = (const float*)d_in[7];
    const float* b2    = (const float*)d_in[8];
    float* out = (float*)d_out;

    char* ws = (char*)d_ws;
    size_t off = 0;
    auto alloc = [&](size_t bytes) -> void* {
        void* p = ws + off;
        off += (bytes + 255) & ~(size_t)255;
        return p;
    };
    ushort* xb    = (ushort*)alloc((size_t)NN * HID * 2);
    ushort* hb    = (ushort*)alloc((size_t)NN * HID * 2);
    int*    ghist = (int*)alloc((size_t)NB * 4);
    int*    boff  = (int*)alloc((size_t)(NB + 1) * 4);
    int*    gcur  = (int*)alloc((size_t)NB * 4);
    int2*   evb   = (int2*)alloc((size_t)NE * 8);
    float*  stats = (float*)alloc(NL * 128 * 4);

    hipMemsetAsync(ghist, 0, (size_t)NB * 4, stream);
    hipMemsetAsync(stats, 0, NL * 128 * 4, stream);

    k_conv<<<(NN * HID / 4 + 255) / 256, 256, 0, stream>>>(x_in, xb);
    k_histB<<<BIN_GRID, 256, 0, stream>>>(ei + NE, ghist);
    k_scanB<<<1, 1024, 0, stream>>>(ghist, boff, gcur);
    k_binB<<<BIN_GRID, 256, 0, stream>>>(ei, att, gcur, evb);

    for (int l = 0; l < NL; ++l) {
        k_agg<<<NB, 512, 0, stream>>>(xb, boff, evb,
                                      W1 + (size_t)l * HID * HID, b1 + l * HID,
                                      hb, stats + l * 128);
        k_mlp2<<<1024, 256, 0, stream>>>(W2 + (size_t)l * HID * HID, b2 + l * HID,
                                         gamma + l * HID, beta + l * HID,
                                         stats + l * 128, hb,
                                         xb, out, (l == NL - 1) ? 1 : 0);
    }
}

// Round 6
// 627.679 us; speedup vs baseline: 3.7249x; 3.7249x over previous
//
#include <hip/hip_runtime.h>

#define NN 100000
#define NE 1600000
#define HID 64
#define NL 3
#define BN_EPS 1e-5f
#define SCAN_B 1024

__device__ __forceinline__ float bf2f(unsigned short u) {
    union { unsigned int i; float f; } v; v.i = ((unsigned int)u) << 16; return v.f;
}
__device__ __forceinline__ unsigned short f2bf(float f) {
    union { float f; unsigned int i; } v; v.f = f;
    unsigned int r = v.i + 0x7FFFu + ((v.i >> 16) & 1u);   // RNE
    return (unsigned short)(r >> 16);
}

// ---------------- input convert x f32 -> bf16 ----------------
__global__ void k_conv(const float* __restrict__ x, ushort* __restrict__ xb) {
    int i = blockIdx.x * blockDim.x + threadIdx.x;   // over NN*HID/4
    float4 v = ((const float4*)x)[i];
    ushort4 o;
    o.x = f2bf(v.x); o.y = f2bf(v.y); o.z = f2bf(v.z); o.w = f2bf(v.w);
    ((ushort4*)xb)[i] = o;
}

// ---------------- CSR build (R3 pipeline) ----------------
__global__ void k_hist(const int* __restrict__ dst, int* __restrict__ counts) {
    int e = blockIdx.x * blockDim.x + threadIdx.x;
    if (e < NE) atomicAdd(&counts[dst[e]], 1);
}

__global__ void k_scan1(const int* __restrict__ counts, int* __restrict__ offs,
                        int* __restrict__ bsum) {
    __shared__ int tmp[SCAN_B];
    int tid = threadIdx.x;
    int gid = blockIdx.x * SCAN_B + tid;
    int v = (gid < NN) ? counts[gid] : 0;
    tmp[tid] = v;
    __syncthreads();
    for (int d = 1; d < SCAN_B; d <<= 1) {
        int t = (tid >= d) ? tmp[tid - d] : 0;
        __syncthreads();
        tmp[tid] += t;
        __syncthreads();
    }
    if (gid < NN) offs[gid] = tmp[tid] - v;
    if (tid == SCAN_B - 1) bsum[blockIdx.x] = tmp[tid];
}

__global__ void k_scan2(int* __restrict__ bsum, int nb) {
    __shared__ int t[128];
    int tid = threadIdx.x;
    int v = (tid < nb) ? bsum[tid] : 0;
    t[tid] = v;
    __syncthreads();
    for (int d = 1; d < 128; d <<= 1) {
        int u = (tid >= d) ? t[tid - d] : 0;
        __syncthreads();
        t[tid] += u;
        __syncthreads();
    }
    if (tid < nb) bsum[tid] = t[tid] - v;
}

__global__ void k_scan3(int* __restrict__ offs, const int* __restrict__ bsum,
                        int* __restrict__ cursor) {
    int gid = blockIdx.x * SCAN_B + threadIdx.x;
    if (gid < NN) {
        int v = offs[gid] + bsum[blockIdx.x];
        offs[gid] = v;
        cursor[gid] = v;
    }
    if (gid == 0) offs[NN] = NE;
}

__global__ void k_scatter(const int* __restrict__ ei, const float* __restrict__ att,
                          int* __restrict__ cursor, int2* __restrict__ ev) {
    int e = blockIdx.x * blockDim.x + threadIdx.x;
    if (e >= NE) return;
    int s = ei[e];
    int d = ei[NE + e];
    float a = att[e];
    int p = atomicAdd(&cursor[d], 1);
    ev[p] = make_int2(s, __float_as_int(a));
}

// ------- gather: quarter-wave per edge, ushort4 row loads, per-node CSR -------
__global__ __launch_bounds__(256, 8) void k_gather(const ushort* __restrict__ xb,
                                                   const int* __restrict__ offs,
                                                   const int2* __restrict__ ev,
                                                   ushort* __restrict__ agg) {
    int tid = threadIdx.x;
    int wv = tid >> 6, lane = tid & 63;
    int g = lane >> 4, li = lane & 15;
    int wave = blockIdx.x * 4 + wv;
    int nw = gridDim.x * 4;
    for (int node = wave; node < NN; node += nw) {
        ushort4 s4 = *(const ushort4*)(xb + (size_t)node * HID + li * 4);
        float4 acc;
        acc.x = (g == 0) ? bf2f(s4.x) : 0.f;
        acc.y = (g == 0) ? bf2f(s4.y) : 0.f;
        acc.z = (g == 0) ? bf2f(s4.z) : 0.f;
        acc.w = (g == 0) ? bf2f(s4.w) : 0.f;
        int e0 = offs[node], e1 = offs[node + 1];
        for (int e = e0; e < e1; e += 8) {      // 8 edges per wave-iter (2 per group)
            int ea = e + g, eb = e + 4 + g;
            int2 ta = ev[(ea < e1) ? ea : (e1 - 1)];
            int2 tb = ev[(eb < e1) ? eb : (e1 - 1)];
            float aa = (ea < e1) ? __int_as_float(ta.y) : 0.f;
            float ab = (eb < e1) ? __int_as_float(tb.y) : 0.f;
            ushort4 ra = *(const ushort4*)(xb + (size_t)ta.x * HID + li * 4);
            ushort4 rb = *(const ushort4*)(xb + (size_t)tb.x * HID + li * 4);
            acc.x += bf2f(ra.x) * aa + bf2f(rb.x) * ab;
            acc.y += bf2f(ra.y) * aa + bf2f(rb.y) * ab;
            acc.z += bf2f(ra.z) * aa + bf2f(rb.z) * ab;
            acc.w += bf2f(ra.w) * aa + bf2f(rb.w) * ab;
        }
        // reduce the 4 quarter-wave partial sums (lanes li, li+16, li+32, li+48)
        acc.x += __shfl_xor(acc.x, 16, 64); acc.x += __shfl_xor(acc.x, 32, 64);
        acc.y += __shfl_xor(acc.y, 16, 64); acc.y += __shfl_xor(acc.y, 32, 64);
        acc.z += __shfl_xor(acc.z, 16, 64); acc.z += __shfl_xor(acc.z, 32, 64);
        acc.w += __shfl_xor(acc.w, 16, 64); acc.w += __shfl_xor(acc.w, 32, 64);
        if (g == 0) {
            ushort4 o;
            o.x = f2bf(acc.x); o.y = f2bf(acc.y); o.z = f2bf(acc.z); o.w = f2bf(acc.w);
            *(ushort4*)(agg + (size_t)node * HID + li * 4) = o;
        }
    }
}

// ------- mlp1: h = agg @ W1 + b1 (W col pinned in VGPRs via volatile), BN stats -------
__global__ __launch_bounds__(256, 4) void k_mlp1(const ushort* __restrict__ agg,
                                                 const float* __restrict__ W1,
                                                 const float* __restrict__ b1,
                                                 ushort* __restrict__ h,
                                                 float* __restrict__ stats) {
    __shared__ float rowlds[4][HID];
    __shared__ float red[8][HID];
    int tid = threadIdx.x, wv = tid >> 6, c = tid & 63;
    float wr[HID];
    {
        volatile const float* wp = W1;       // volatile: forbid remat -> stays in VGPRs
#pragma unroll
        for (int k = 0; k < HID; ++k) wr[k] = wp[k * HID + c];
    }
    float bl = b1[c];
    float s1 = 0.f, s2 = 0.f;
    int gw = blockIdx.x * 4 + wv, nw = gridDim.x * 4;
    for (int node = gw; node < NN; node += nw) {
        rowlds[wv][c] = bf2f(agg[(size_t)node * HID + c]);
        float o = bl;
        const float4* rp = (const float4*)&rowlds[wv][0];
#pragma unroll
        for (int k4 = 0; k4 < 16; ++k4) {
            float4 rv = rp[k4];
            o += rv.x * wr[4 * k4] + rv.y * wr[4 * k4 + 1]
               + rv.z * wr[4 * k4 + 2] + rv.w * wr[4 * k4 + 3];
        }
        h[(size_t)node * HID + c] = f2bf(o);
        s1 += o;
        s2 += o * o;
    }
    red[wv][c] = s1;
    red[4 + wv][c] = s2;
    __syncthreads();
    if (wv == 0) {
        atomicAdd(&stats[c], red[0][c] + red[1][c] + red[2][c] + red[3][c]);
        atomicAdd(&stats[HID + c], red[4][c] + red[5][c] + red[6][c] + red[7][c]);
    }
}

// ------- mlp2: BN -> ReLU -> Linear2 -> ReLU; out bf16 (mid) or f32 (last) -------
__global__ __launch_bounds__(256, 4) void k_mlp2(const float* __restrict__ W2,
                                                 const float* __restrict__ b2,
                                                 const float* __restrict__ gamma,
                                                 const float* __restrict__ beta,
                                                 const float* __restrict__ stats,
                                                 const ushort* __restrict__ h,
                                                 ushort* __restrict__ xb_out,
                                                 float* __restrict__ f_out,
                                                 int write_f32) {
    __shared__ float rowlds[4][HID];
    int tid = threadIdx.x, wv = tid >> 6, c = tid & 63;
    float wr[HID];
    {
        volatile const float* wp = W2;
#pragma unroll
        for (int k = 0; k < HID; ++k) wr[k] = wp[k * HID + c];
    }
    float bl = b2[c];
    float mu = stats[c] * (1.0f / NN);
    float var = fmaxf(stats[HID + c] * (1.0f / NN) - mu * mu, 0.f);
    float aC = gamma[c] * rsqrtf(var + BN_EPS);
    float bC = beta[c] - mu * aC;
    int gw = blockIdx.x * 4 + wv, nw = gridDim.x * 4;
    for (int node = gw; node < NN; node += nw) {
        float v = bf2f(h[(size_t)node * HID + c]);
        v = fmaxf(aC * v + bC, 0.f);
        rowlds[wv][c] = v;                    // wave-local buffer, no barrier
        float o = bl;
        const float4* rp = (const float4*)&rowlds[wv][0];
#pragma unroll
        for (int k4 = 0; k4 < 16; ++k4) {
            float4 rv = rp[k4];
            o += rv.x * wr[4 * k4] + rv.y * wr[4 * k4 + 1]
               + rv.z * wr[4 * k4 + 2] + rv.w * wr[4 * k4 + 3];
        }
        o = fmaxf(o, 0.f);
        if (write_f32) f_out[(size_t)node * HID + c] = o;
        else           xb_out[(size_t)node * HID + c] = f2bf(o);
    }
}

extern "C" void kernel_launch(void* const* d_in, const int* in_sizes, int n_in,
                              void* d_out, int out_size, void* d_ws, size_t ws_size,
                              hipStream_t stream) {
    const float* x_in  = (const float*)d_in[0];
    const int*   ei    = (const int*)d_in[1];
    const float* att   = (const float*)d_in[2];
    const float* W1    = (const float*)d_in[3];
    const float* b1    = (const float*)d_in[4];
    const float* gamma = (const float*)d_in[5];
    const float* beta  = (const float*)d_in[6];
    const float* W2    = (const float*)d_in[7];
    const float* b2    = (const float*)d_in[8];
    float* out = (float*)d_out;

    char* ws = (char*)d_ws;
    size_t off = 0;
    auto alloc = [&](size_t bytes) -> void* {
        void* p = ws + off;
        off += (bytes + 255) & ~(size_t)255;
        return p;
    };
    ushort* xb    = (ushort*)alloc((size_t)NN * HID * 2);
    ushort* aggb  = (ushort*)alloc((size_t)NN * HID * 2);
    ushort* hb    = (ushort*)alloc((size_t)NN * HID * 2);
    int*    counts= (int*)alloc((size_t)NN * 4);
    int*    offs  = (int*)alloc((size_t)(NN + 1) * 4);
    int*    cursor= (int*)alloc((size_t)NN * 4);
    int2*   ev    = (int2*)alloc((size_t)NE * 8);
    int*    bsum  = (int*)alloc(4096);
    float*  stats = (float*)alloc(NL * 128 * 4);

    hipMemsetAsync(counts, 0, (size_t)NN * 4, stream);
    hipMemsetAsync(stats, 0, NL * 128 * 4, stream);

    k_conv<<<(NN * HID / 4 + 255) / 256, 256, 0, stream>>>(x_in, xb);

    int nb = (NN + SCAN_B - 1) / SCAN_B;
    k_hist<<<(NE + 255) / 256, 256, 0, stream>>>(ei + NE, counts);
    k_scan1<<<nb, SCAN_B, 0, stream>>>(counts, offs, bsum);
    k_scan2<<<1, 128, 0, stream>>>(bsum, nb);
    k_scan3<<<nb, SCAN_B, 0, stream>>>(offs, bsum, cursor);
    k_scatter<<<(NE + 255) / 256, 256, 0, stream>>>(ei, att, cursor, ev);

    for (int l = 0; l < NL; ++l) {
        k_gather<<<2048, 256, 0, stream>>>(xb, offs, ev, aggb);
        k_mlp1<<<1024, 256, 0, stream>>>(aggb, W1 + (size_t)l * HID * HID,
                                         b1 + l * HID, hb, stats + l * 128);
        k_mlp2<<<1024, 256, 0, stream>>>(W2 + (size_t)l * HID * HID, b2 + l * HID,
                                         gamma + l * HID, beta + l * HID,
                                         stats + l * 128, hb,
                                         xb, out, (l == NL - 1) ? 1 : 0);
    }
}